// Round 4
// baseline (103.351 us; speedup 1.0000x reference)
//
#include <hip/hip_runtime.h>
#include <hip/hip_bf16.h>

// LocallyConnected2d: B=16, C=32, O=32, H=W=64, K=3x3, pad=1, stride=1.
// out[b,o,h,w] = sum_{c,k} x[b,c,h+dh,w+dw] * weight[o,c,h,w,k]
//
// R4: explicit register software-pipelining to kill latency stalls (R3 was
// 80% dep-stall: VALU work ~9us, DS work ~10us, measured 88us).
//  - x prefetched one full c ahead (X0/X1 double buffer, 24 regs)
//  - weights double-buffered one c ahead
//  - bpermutes pipelined 2 b-steps deep (pr[2][6]) -> ds latency covered
//  - __launch_bounds__(256,4): cap VGPR at 128, keep 4 blocks/CU

#define CIN  32
#define OCH  32
#define HH   64
#define WW   64
#define BB   8    // batches per thread
#define OO   2    // output channels per thread
#define CC   16   // input channels per block (c-split 2)

typedef float f32x4 __attribute__((ext_vector_type(4), aligned(4)));

__device__ __forceinline__ float lane_pick(int byte_addr, float v) {
    return __int_as_float(__builtin_amdgcn_ds_bpermute(byte_addr, __float_as_int(v)));
}

#define WSTRC ((size_t)HH * WW * 9)
#define WSTRO ((size_t)CIN * WSTRC)
#define XB    ((size_t)CIN * HH * WW)

__device__ __forceinline__ void step(
    int c, const float* __restrict__ wpa, const float* __restrict__ wpb,
    const float* __restrict__ xbase,
    float (&XC)[3][BB], float (&XN)[3][BB],
    f32x4& cA03, f32x4& cA47, float& cA8,
    f32x4& cB03, f32x4& cB47, float& cB8,
    f32x4& nA03, f32x4& nA47, float& nA8,
    f32x4& nB03, f32x4& nB47, float& nB8,
    float (&acc)[OO * BB],
    int ro0, int ro1, int ro2, int lup, int ldn,
    float mt, float mb, float ml, float mr,
    float mtml, float mtmr, float mbml, float mbmr)
{
    // ---- prefetch c+1 (weights + x) : consumed next call ----
    const int cn = (c + 1 < CC) ? c + 1 : c;
    const float* npa = wpa + (size_t)cn * WSTRC;
    const float* npb = wpb + (size_t)cn * WSTRC;
    nA03 = *(const f32x4*)(npa);
    nA47 = *(const f32x4*)(npa + 4);
    nA8  = npa[8];
    nB03 = *(const f32x4*)(npb);
    nB47 = *(const f32x4*)(npb + 4);
    nB8  = npb[8];

    const float* xnb = xbase + (size_t)cn * (HH * WW);
#pragma unroll
    for (int b = 0; b < BB; ++b) {
        const float* xp = xnb + (size_t)b * XB;
        XN[0][b] = xp[ro0]; XN[1][b] = xp[ro1]; XN[2][b] = xp[ro2];
    }

    // ---- fold edge masks into current-c weights ----
    const float wa0 = cA03.x * mtml, wa1 = cA03.y * mt, wa2 = cA03.z * mtmr;
    const float wa3 = cA03.w * ml,   wa4 = cA47.x,      wa5 = cA47.y * mr;
    const float wa6 = cA47.z * mbml, wa7 = cA47.w * mb, wa8 = cA8 * mbmr;
    const float wb0 = cB03.x * mtml, wb1 = cB03.y * mt, wb2 = cB03.z * mtmr;
    const float wb3 = cB03.w * ml,   wb4 = cB47.x,      wb5 = cB47.y * mr;
    const float wb6 = cB47.z * mbml, wb7 = cB47.w * mb, wb8 = cB8 * mbmr;

    // ---- bperm pipelined 2 deep over b ----
    float pr[2][6];
#pragma unroll
    for (int b = 0; b < 2; ++b) {
        pr[b][0] = lane_pick(lup, XC[0][b]); pr[b][1] = lane_pick(ldn, XC[0][b]);
        pr[b][2] = lane_pick(lup, XC[1][b]); pr[b][3] = lane_pick(ldn, XC[1][b]);
        pr[b][4] = lane_pick(lup, XC[2][b]); pr[b][5] = lane_pick(ldn, XC[2][b]);
    }
#pragma unroll
    for (int b = 0; b < BB; ++b) {
        const float xtl = pr[b & 1][0], xtr = pr[b & 1][1];
        const float xml = pr[b & 1][2], xmr = pr[b & 1][3];
        const float xdl = pr[b & 1][4], xdr = pr[b & 1][5];
        const float xt = XC[0][b], xm = XC[1][b], xd = XC[2][b];

        float a = acc[b];
        a = fmaf(xtl, wa0, a); a = fmaf(xt, wa1, a); a = fmaf(xtr, wa2, a);
        a = fmaf(xml, wa3, a); a = fmaf(xm, wa4, a); a = fmaf(xmr, wa5, a);
        a = fmaf(xdl, wa6, a); a = fmaf(xd, wa7, a); a = fmaf(xdr, wa8, a);
        acc[b] = a;

        float q = acc[BB + b];
        q = fmaf(xtl, wb0, q); q = fmaf(xt, wb1, q); q = fmaf(xtr, wb2, q);
        q = fmaf(xml, wb3, q); q = fmaf(xm, wb4, q); q = fmaf(xmr, wb5, q);
        q = fmaf(xdl, wb6, q); q = fmaf(xd, wb7, q); q = fmaf(xdr, wb8, q);
        acc[BB + b] = q;

        if (b + 2 < BB) {
            pr[b & 1][0] = lane_pick(lup, XC[0][b + 2]);
            pr[b & 1][1] = lane_pick(ldn, XC[0][b + 2]);
            pr[b & 1][2] = lane_pick(lup, XC[1][b + 2]);
            pr[b & 1][3] = lane_pick(ldn, XC[1][b + 2]);
            pr[b & 1][4] = lane_pick(lup, XC[2][b + 2]);
            pr[b & 1][5] = lane_pick(ldn, XC[2][b + 2]);
        }
    }
}

__global__ __launch_bounds__(256, 4)
void lc2d_kernel(const float* __restrict__ x,
                 const float* __restrict__ wt,
                 float* __restrict__ out) {
    const int w  = threadIdx.x;                 // lane == w
    const int h  = blockIdx.x * 4 + threadIdx.y;
    const int o0 = blockIdx.y * OO;
    const int bz = blockIdx.z & 1;              // batch half
    const int cg = blockIdx.z >> 1;             // c half
    const int b0 = bz * BB;
    const int c0 = cg * CC;

    const float mt = (h > 0)      ? 1.f : 0.f;
    const float mb = (h < HH - 1) ? 1.f : 0.f;
    const float ml = (w > 0)      ? 1.f : 0.f;
    const float mr = (w < WW - 1) ? 1.f : 0.f;
    const float mtml = mt * ml, mtmr = mt * mr, mbml = mb * ml, mbmr = mb * mr;
    const int iht = (h > 0)      ? h - 1 : 0;
    const int ihb = (h < HH - 1) ? h + 1 : HH - 1;
    const int lup = ((w > 0)  ? w - 1 : 0)  << 2;
    const int ldn = ((w < 63) ? w + 1 : 63) << 2;

    const int ro0 = iht * WW + w, ro1 = h * WW + w, ro2 = ihb * WW + w;
    const float* xbase = x + ((size_t)b0 * CIN + c0) * (HH * WW);

    const float* wpa = wt + (size_t)o0 * WSTRO + (size_t)c0 * WSTRC
                          + ((size_t)h * WW + w) * 9;
    const float* wpb = wpa + WSTRO;

    float acc[OO * BB];
#pragma unroll
    for (int i = 0; i < OO * BB; ++i) acc[i] = 0.f;

    float X0[3][BB], X1[3][BB];
    f32x4 A0_03, A0_47, B0_03, B0_47, A1_03, A1_47, B1_03, B1_47;
    float A0_8, B0_8, A1_8, B1_8;

    // prologue: load c=0 weights + x
    A0_03 = *(const f32x4*)(wpa); A0_47 = *(const f32x4*)(wpa + 4); A0_8 = wpa[8];
    B0_03 = *(const f32x4*)(wpb); B0_47 = *(const f32x4*)(wpb + 4); B0_8 = wpb[8];
#pragma unroll
    for (int b = 0; b < BB; ++b) {
        const float* xp = xbase + (size_t)b * XB;
        X0[0][b] = xp[ro0]; X0[1][b] = xp[ro1]; X0[2][b] = xp[ro2];
    }

    for (int c = 0; c < CC; c += 2) {
        step(c,     wpa, wpb, xbase, X0, X1,
             A0_03, A0_47, A0_8, B0_03, B0_47, B0_8,
             A1_03, A1_47, A1_8, B1_03, B1_47, B1_8,
             acc, ro0, ro1, ro2, lup, ldn,
             mt, mb, ml, mr, mtml, mtmr, mbml, mbmr);
        step(c + 1, wpa, wpb, xbase, X1, X0,
             A1_03, A1_47, A1_8, B1_03, B1_47, B1_8,
             A0_03, A0_47, A0_8, B0_03, B0_47, B0_8,
             acc, ro0, ro1, ro2, lup, ldn,
             mt, mb, ml, mr, mtml, mtmr, mbml, mbmr);
    }

#pragma unroll
    for (int b = 0; b < BB; ++b) {
#pragma unroll
        for (int oo = 0; oo < OO; ++oo) {
            atomicAdd(out + (((size_t)(b0 + b) * OCH + (o0 + oo)) * HH + h) * WW + w,
                      acc[oo * BB + b]);
        }
    }
}

extern "C" void kernel_launch(void* const* d_in, const int* in_sizes, int n_in,
                              void* d_out, int out_size, void* d_ws, size_t ws_size,
                              hipStream_t stream) {
    const float* x  = (const float*)d_in[0];
    const float* wt = (const float*)d_in[1];
    float* out = (float*)d_out;

    hipMemsetAsync(out, 0, (size_t)out_size * sizeof(float), stream);

    dim3 block(64, 4);
    dim3 grid(HH / 4, OCH / OO, 4);   // 16 x 16 x (2 batch-halves * 2 c-halves)
    lc2d_kernel<<<grid, block, 0, stream>>>(x, wt, out);
}

// Round 5
// 57.368 us; speedup vs baseline: 1.8016x; 1.8016x over previous
//
#include <hip/hip_runtime.h>
#include <hip/hip_bf16.h>

// LocallyConnected2d: B=16, C=32, O=32, H=W=64, K=3x3, pad=1, stride=1.
// out[b,o,h,w] = sum_{c,k} x[b,c,h+dh,w+dw] * weight[o,c,h,w,k]
//
// R5: R3 structure (known-good 59us, VGPR=44) + occupancy fix.
//  - R4's register pipelining SPILLED (VGPR cap 64, ~150 live -> scratch:
//    FETCH 105->249MB, WRITE 16->63MB). Reverted entirely.
//  - R3 was grid-limited: 1024 blocks = 4 blocks/CU -> occupancy 40%.
//    c-split x4 (CC=8) -> 2048 blocks -> 8 blocks/CU, 8 waves/SIMD
//    (VGPR must stay <=64; weight double-buffer dropped to guarantee it).
//  - 4 atomic addends per output (commutative f32, within absmax threshold).

#define CIN  32
#define OCH  32
#define HH   64
#define WW   64
#define BB   8    // batches per thread
#define OO   2    // output channels per thread
#define CC   8    // input channels per block (c-split 4)

typedef float f32x4 __attribute__((ext_vector_type(4), aligned(4)));

__device__ __forceinline__ float lane_pick(int byte_addr, float v) {
    return __int_as_float(__builtin_amdgcn_ds_bpermute(byte_addr, __float_as_int(v)));
}

#define WSTRC ((size_t)HH * WW * 9)    // per-c weight stride (floats)
#define WSTRO ((size_t)CIN * WSTRC)    // per-o weight stride
#define XB    ((size_t)CIN * HH * WW)  // per-batch x stride

__global__ __launch_bounds__(256)
void lc2d_kernel(const float* __restrict__ x,
                 const float* __restrict__ wt,
                 float* __restrict__ out) {
    const int w  = threadIdx.x;                 // 0..63, lane == w
    const int h  = blockIdx.x * 4 + threadIdx.y;
    const int o0 = blockIdx.y * OO;
    const int bz = blockIdx.z & 1;              // batch half
    const int cg = blockIdx.z >> 1;             // c quarter
    const int b0 = bz * BB;
    const int c0 = cg * CC;

    // edge masks folded into weights; clamped indices keep loads legal
    const float mt = (h > 0)      ? 1.f : 0.f;
    const float mb = (h < HH - 1) ? 1.f : 0.f;
    const float ml = (w > 0)      ? 1.f : 0.f;
    const float mr = (w < WW - 1) ? 1.f : 0.f;
    const float mtml = mt * ml, mtmr = mt * mr, mbml = mb * ml, mbmr = mb * mr;
    const int iht = (h > 0)      ? h - 1 : 0;
    const int ihb = (h < HH - 1) ? h + 1 : HH - 1;

    const int lup = ((w > 0)  ? w - 1 : 0)  << 2;
    const int ldn = ((w < 63) ? w + 1 : 63) << 2;

    const int ro_t = iht * WW + w;
    const int ro_m = h   * WW + w;
    const int ro_b = ihb * WW + w;

    float acc[OO * BB];
#pragma unroll
    for (int i = 0; i < OO * BB; ++i) acc[i] = 0.f;

    const float* wpa0 = wt + (size_t)o0 * WSTRO + (size_t)c0 * WSTRC
                           + ((size_t)h * WW + w) * 9;
    const float* xb0 = x + ((size_t)b0 * CIN + c0) * (HH * WW);

    for (int c = 0; c < CC; ++c) {
        const float* wpa = wpa0 + (size_t)c * WSTRC;
        const float* wpb = wpa + WSTRO;
        f32x4 a03 = *(const f32x4*)(wpa);
        f32x4 a47 = *(const f32x4*)(wpa + 4);
        float a8  = wpa[8];
        f32x4 b03 = *(const f32x4*)(wpb);
        f32x4 b47 = *(const f32x4*)(wpb + 4);
        float b8  = wpb[8];

        const float wa0 = a03.x * mtml, wa1 = a03.y * mt, wa2 = a03.z * mtmr;
        const float wa3 = a03.w * ml,   wa4 = a47.x,      wa5 = a47.y * mr;
        const float wa6 = a47.z * mbml, wa7 = a47.w * mb, wa8 = a8 * mbmr;
        const float wb0 = b03.x * mtml, wb1 = b03.y * mt, wb2 = b03.z * mtmr;
        const float wb3 = b03.w * ml,   wb4 = b47.x,      wb5 = b47.y * mr;
        const float wb6 = b47.z * mbml, wb7 = b47.w * mb, wb8 = b8 * mbmr;

        const float* xc = xb0 + (size_t)c * (HH * WW);
#pragma unroll
        for (int b = 0; b < BB; ++b) {
            const float* xp = xc + (size_t)b * XB;
            const float xt = xp[ro_t];
            const float xm = xp[ro_m];
            const float xd = xp[ro_b];
            const float xtl = lane_pick(lup, xt), xtr = lane_pick(ldn, xt);
            const float xml = lane_pick(lup, xm), xmr = lane_pick(ldn, xm);
            const float xdl = lane_pick(lup, xd), xdr = lane_pick(ldn, xd);

            float a = acc[b];
            a = fmaf(xtl, wa0, a); a = fmaf(xt, wa1, a); a = fmaf(xtr, wa2, a);
            a = fmaf(xml, wa3, a); a = fmaf(xm, wa4, a); a = fmaf(xmr, wa5, a);
            a = fmaf(xdl, wa6, a); a = fmaf(xd, wa7, a); a = fmaf(xdr, wa8, a);
            acc[b] = a;

            float q = acc[BB + b];
            q = fmaf(xtl, wb0, q); q = fmaf(xt, wb1, q); q = fmaf(xtr, wb2, q);
            q = fmaf(xml, wb3, q); q = fmaf(xm, wb4, q); q = fmaf(xmr, wb5, q);
            q = fmaf(xdl, wb6, q); q = fmaf(xd, wb7, q); q = fmaf(xdr, wb8, q);
            acc[BB + b] = q;
        }
    }

#pragma unroll
    for (int b = 0; b < BB; ++b) {
#pragma unroll
        for (int oo = 0; oo < OO; ++oo) {
            atomicAdd(out + (((size_t)(b0 + b) * OCH + (o0 + oo)) * HH + h) * WW + w,
                      acc[oo * BB + b]);
        }
    }
}

extern "C" void kernel_launch(void* const* d_in, const int* in_sizes, int n_in,
                              void* d_out, int out_size, void* d_ws, size_t ws_size,
                              hipStream_t stream) {
    const float* x  = (const float*)d_in[0];
    const float* wt = (const float*)d_in[1];
    float* out = (float*)d_out;

    hipMemsetAsync(out, 0, (size_t)out_size * sizeof(float), stream);

    dim3 block(64, 4);
    dim3 grid(HH / 4, OCH / OO, 8);   // 16 x 16 x (2 batch-halves * 4 c-quarters)
    lc2d_kernel<<<grid, block, 0, stream>>>(x, wt, out);
}